// Round 5
// baseline (26.832 us; speedup 1.0000x reference)
//
#include <hip/hip_runtime.h>

// X = prod_{i=0}^{n-1} (I + A_i/n), left-to-right, A: [N,2,2] f32 row-major.
// R4 post-mortem: coalesced tree tail cut 37.8->23.6us (phase2 strided tail
// confirmed). R5: the two remaining tree kernels are pure launch latency
// (125KB of work) -> fuse into ONE single-block kernel. Dispatches 3->2.

struct M2 { double a, b, c, d; };  // [[a,b],[c,d]]

__device__ __forceinline__ M2 m2mul(const M2& X, const M2& Y) {
    M2 r;
    r.a = fma(X.a, Y.a, X.b * Y.c);
    r.b = fma(X.a, Y.b, X.b * Y.d);
    r.c = fma(X.c, Y.a, X.d * Y.c);
    r.d = fma(X.c, Y.b, X.d * Y.d);
    return r;
}

__device__ __forceinline__ M2 from_f4(float4 v, double inv_n) {
    M2 M;
    M.a = fma((double)v.x, inv_n, 1.0);
    M.b = (double)v.y * inv_n;
    M.c = (double)v.z * inv_n;
    M.d = fma((double)v.w, inv_n, 1.0);
    return M;
}

// Ordered wave tree combine: lower lane = earlier chunk = left operand.
__device__ __forceinline__ M2 wave_combine(M2 P) {
    #pragma unroll
    for (int off = 1; off < 64; off <<= 1) {
        M2 Q;
        Q.a = __shfl_down(P.a, off);
        Q.b = __shfl_down(P.b, off);
        Q.c = __shfl_down(P.c, off);
        Q.d = __shfl_down(P.d, off);
        P = m2mul(P, Q);
    }
    return P;
}

__device__ __forceinline__ M2 load_m2(const double* p) {
    double2 lo = *reinterpret_cast<const double2*>(p);
    double2 hi = *reinterpret_cast<const double2*>(p + 2);
    M2 Q = { lo.x, lo.y, hi.x, hi.y };
    return Q;
}

__device__ __forceinline__ void store_m2(double* p, const M2& P) {
    *reinterpret_cast<double2*>(p)     = double2{ P.a, P.b };
    *reinterpret_cast<double2*>(p + 2) = double2{ P.c, P.d };
}

#define CHUNK 5
#define P1_TPB 256
#define TILE (P1_TPB * CHUNK)          // 1280 matrices per block, 20 KB LDS

__global__ void __launch_bounds__(P1_TPB) prodchain_phase1(
    const float4* __restrict__ A, int n, double* __restrict__ part)
{
    __shared__ float4 tile[TILE];
    __shared__ double bl[4 * 4];       // 4 wave partials
    const int tid = threadIdx.x;
    const int blockStart = blockIdx.x * TILE;
    const double inv_n = 1.0 / (double)n;

    // Coalesced stage: granule k*256+tid; consecutive lanes 16B apart.
    float4 r[CHUNK];
    #pragma unroll
    for (int k = 0; k < CHUNK; ++k) {
        int g = blockStart + k * P1_TPB + tid;
        r[k] = (g < n) ? A[g] : make_float4(0.f, 0.f, 0.f, 0.f);
    }
    #pragma unroll
    for (int k = 0; k < CHUNK; ++k)
        tile[k * P1_TPB + tid] = r[k];
    __syncthreads();

    // Consume contiguous per-thread chunk from LDS. Lane stride 80B ->
    // 16B-group pattern (5l)%8 is a permutation: conflict-free b128 reads.
    M2 P = {1.0, 0.0, 0.0, 1.0};
    const int base = tid * CHUNK;
    #pragma unroll
    for (int j = 0; j < CHUNK; ++j) {
        int gi = blockStart + base + j;
        if (gi < n) P = m2mul(P, from_f4(tile[base + j], inv_n));
    }

    P = wave_combine(P);

    const int w = tid >> 6;
    if ((tid & 63) == 0) {
        bl[4 * w + 0] = P.a;
        bl[4 * w + 1] = P.b;
        bl[4 * w + 2] = P.c;
        bl[4 * w + 3] = P.d;
    }
    __syncthreads();

    if (tid == 0) {
        M2 R = { bl[0], bl[1], bl[2], bl[3] };
        #pragma unroll
        for (int w2 = 1; w2 < 4; ++w2) {
            M2 Q = { bl[4 * w2 + 0], bl[4 * w2 + 1],
                     bl[4 * w2 + 2], bl[4 * w2 + 3] };
            R = m2mul(R, Q);
        }
        store_m2(&part[4 * blockIdx.x], R);
    }
}

#define P2_TPB 1024

// Single block. np block-partials (L3-resident, 125 KB). Thread t serially
// combines partials [t*per, t*per+per) (identity for OOB), wave tree, LDS
// cross-wave combine in wave order, write 4 floats.
__global__ void __launch_bounds__(P2_TPB) prodchain_tail(
    const double* __restrict__ part, int np, float* __restrict__ out)
{
    __shared__ double lds[4 * (P2_TPB / 64)];
    const int t = threadIdx.x;
    const int per = (np + P2_TPB - 1) / P2_TPB;   // 4 for np=3907
    M2 P = {1.0, 0.0, 0.0, 1.0};
    const int base = t * per;
    for (int j = 0; j < per; ++j) {
        int i = base + j;
        if (i < np) P = m2mul(P, load_m2(&part[4 * i]));
    }

    P = wave_combine(P);

    const int w = t >> 6;
    if ((t & 63) == 0) {
        lds[4 * w + 0] = P.a;
        lds[4 * w + 1] = P.b;
        lds[4 * w + 2] = P.c;
        lds[4 * w + 3] = P.d;
    }
    __syncthreads();

    if (t == 0) {
        M2 R = { lds[0], lds[1], lds[2], lds[3] };
        #pragma unroll
        for (int w2 = 1; w2 < P2_TPB / 64; ++w2) {
            M2 Q = { lds[4 * w2 + 0], lds[4 * w2 + 1],
                     lds[4 * w2 + 2], lds[4 * w2 + 3] };
            R = m2mul(R, Q);
        }
        out[0] = (float)R.a;
        out[1] = (float)R.b;
        out[2] = (float)R.c;
        out[3] = (float)R.d;
    }
}

extern "C" void kernel_launch(void* const* d_in, const int* in_sizes, int n_in,
                              void* d_out, int out_size, void* d_ws, size_t ws_size,
                              hipStream_t stream) {
    const float4* A = (const float4*)d_in[0];
    const int n = in_sizes[0] / 4;                    // 5,000,000 matrices
    const int nb1 = (n + TILE - 1) / TILE;            // 3907 block partials

    double* part = (double*)d_ws;                     // 3907 * 32 B = 125 KB

    prodchain_phase1<<<nb1, P1_TPB, 0, stream>>>(A, n, part);
    prodchain_tail<<<1, P2_TPB, 0, stream>>>(part, nb1, (float*)d_out);
}